// Round 19
// baseline (127.414 us; speedup 1.0000x reference)
//
#include <hip/hip_runtime.h>

// DeepSets fused kernel for MI355X (gfx950) — round 19.
// r18: 102.3 = phi 85.8 + non-phi 16.5. Measured (r12 vs r16): tail NODE
// overhead (gap+launch) ~10.7us >> tail exec (~5us now). So: fuse the NEW
// f16x4 tail into phi via r16's proven last-block machinery (counter@gsum[256],
// threadfence acquire/release), re-parameterized for 512 threads, part[] and
// activations carved from dead h1s. 2 graph nodes. phi hot loop byte-identical.

typedef unsigned short u16;
typedef _Float16 f16x8 __attribute__((ext_vector_type(8)));
typedef _Float16 f16x4v __attribute__((ext_vector_type(4)));
typedef float f32x4 __attribute__((ext_vector_type(4)));
typedef int i32x4 __attribute__((ext_vector_type(4)));

#define NBLK 256

// packed fp16 tail-weight offsets (elements); all divisible by 4
#define OPW3 0        // 256x128
#define ORW1 32768    // 128x256
#define ORW2 65536    // 256x256
#define ORW3 131072   // 256x128
#define OHW1 163840   // 144x256
#define OHW2 200704   // 256x256
#define OHW3 266240   // 256x5
#define NTW  267520

// ---------------- prep: phi-weight fragments + packed fp16 tail weights ------
// Fragment layout (validated r1-r12): lane l, elem j holds W[k=32*ks+8*(l>>4)+j][16*ctg+(l&15)]
// at frag[((ctg*KS+ks)*64 + l)*8 + j]. Used as MFMA *A* operand: D = W^T X^T = (XW)^T.
__global__ void prep_kernel(const float* __restrict__ pw1, const float* __restrict__ pw2,
                            _Float16* __restrict__ w1f, _Float16* __restrict__ w2f,
                            float* __restrict__ gsum, _Float16* __restrict__ tw,
                            const float* __restrict__ pw3, const float* __restrict__ rw1,
                            const float* __restrict__ rw2, const float* __restrict__ rw3,
                            const float* __restrict__ hw1, const float* __restrict__ hw2,
                            const float* __restrict__ hw3) {
    int idx = blockIdx.x * blockDim.x + threadIdx.x;   // 160*512 = 81920
    if (idx < 260) gsum[idx] = 0.f;                    // gsum[256] + counter
    if (idx < 16384) {  // pw1: 64x256, KS=2
        int j = idx & 7, l = (idx >> 3) & 63, ks = (idx >> 9) & 1, ct = idx >> 10;
        int k = 32 * ks + 8 * (l >> 4) + j;
        int col = 16 * ct + (l & 15);
        w1f[idx] = (_Float16)pw1[k * 256 + col];
    } else {            // pw2: 256x256, KS=8
        int o = idx - 16384;
        int j = o & 7, l = (o >> 3) & 63, ks = (o >> 9) & 7, ct = o >> 12;
        int k = 32 * ks + 8 * (l >> 4) + j;
        int col = 16 * ct + (l & 15);
        w2f[o] = (_Float16)pw2[k * 256 + col];
    }
    // pack rho/head weights to fp16, float4 -> f16x4 (write also L3-warms)
    if (idx < NTW / 4) {
        int r = idx * 4;
        const float* src;
        if (r < ORW1)      src = pw3 + r;
        else if (r < ORW2) src = rw1 + (r - ORW1);
        else if (r < ORW3) src = rw2 + (r - ORW2);
        else if (r < OHW1) src = rw3 + (r - ORW3);
        else if (r < OHW2) src = hw1 + (r - OHW1);
        else if (r < OHW3) src = hw2 + (r - OHW2);
        else               src = hw3 + (r - OHW3);
        float4 v = *(const float4*)src;
        uint2 o;
        o.x = __builtin_bit_cast(unsigned, __builtin_amdgcn_cvt_pkrtz(v.x, v.y));
        o.y = __builtin_bit_cast(unsigned, __builtin_amdgcn_cvt_pkrtz(v.z, v.w));
        *(uint2*)(tw + r) = o;
    }
}

__device__ __forceinline__ void pin_reg(f16x8& v) {
    i32x4 t = __builtin_bit_cast(i32x4, v);
    asm volatile("" : "+v"(t));
    v = __builtin_bit_cast(f16x8, t);
}
__device__ __forceinline__ unsigned pk(float a, float b) {
    return __builtin_bit_cast(unsigned, __builtin_amdgcn_cvt_pkrtz(a, b));
}

// f16x4-vectorized split-K layer for the 512-thread fused tail.
// thread: 4 output cols (cg) x KR input rows (slice q); KQ slices total.
#define LAYER_V4(OUT, OFF, INEXPR, BIASEXPR, OUTARR, DORELU, KQ, KR)           \
    {                                                                          \
        int cg = t & ((OUT) / 4 - 1), q = t / ((OUT) / 4);                     \
        float4 s = make_float4(0.f, 0.f, 0.f, 0.f);                            \
        int i0 = q * (KR);                                                     \
        for (int i = i0; i < i0 + (KR); ++i) {                                 \
            f16x4v wv = *(const f16x4v*)(tw + (OFF) + i * (OUT) + 4 * cg);     \
            float xv = INEXPR;                                                 \
            s.x += xv * (float)wv[0]; s.y += xv * (float)wv[1];                \
            s.z += xv * (float)wv[2]; s.w += xv * (float)wv[3];                \
        }                                                                      \
        *(float4*)&part[q * (OUT) + 4 * cg] = s;                               \
    }                                                                          \
    __syncthreads();                                                           \
    if (t < (OUT)) {                                                           \
        float s = BIASEXPR;                                                    \
        for (int q = 0; q < (KQ); ++q) s += part[q * (OUT) + t];               \
        OUTARR[t] = (DORELU) ? fmaxf(s, 0.f) : s;                              \
    }                                                                          \
    __syncthreads();

// ---------------- fused phi + pool + (last block) f16x4 tail -----------------
// 8 waves; wave w owns cols [32w, 32w+32); dbuf xs + dbuf h1s, ONE barrier/iter.
__global__ __attribute__((amdgpu_flat_work_group_size(512, 512), amdgpu_waves_per_eu(2, 2)))
void phi_kernel(
    const float* __restrict__ x,
    const float* __restrict__ pb1, const float* __restrict__ pb2,
    const _Float16* __restrict__ w1g, const _Float16* __restrict__ w2g,
    float* __restrict__ gsum, int ntiles,
    const float* __restrict__ xst, const _Float16* __restrict__ tw,
    const float* __restrict__ pb3, const float* __restrict__ rb1,
    const float* __restrict__ rb2, const float* __restrict__ rb3,
    const float* __restrict__ hb1, const float* __restrict__ hb2,
    const float* __restrict__ hb3,
    float* __restrict__ outp, float nf) {
    __shared__ __align__(16) u16 xs[2][64 * 64];    // x tile fp16, swz ^((row&7)<<4)
    __shared__ __align__(16) u16 h1s[2][64 * 256];  // h1 tile fp16, swz ^((row&15)<<4)
    __shared__ int lastflag;

    const int tid = threadIdx.x;
    const int l = tid & 63;
    const int w = tid >> 6;
    const int fr = l & 15;
    const int fg = l >> 4;
    const int wb = w * 32;

    // ---- preload weight fragments into registers (loop-invariant, pinned)
    f16x8 w1r[2][2];   // [ct][ks]
#pragma unroll
    for (int ct = 0; ct < 2; ++ct)
#pragma unroll
        for (int ks = 0; ks < 2; ++ks) {
            int ctg = 2 * w + ct;
            w1r[ct][ks] = *(const f16x8*)(w1g + (((ctg << 1) + ks) << 9) + (l << 3));
        }
    f16x8 w2r[2][8];   // [ct][ks]
#pragma unroll
    for (int ct = 0; ct < 2; ++ct)
#pragma unroll
        for (int ks = 0; ks < 8; ++ks) {
            int ctg = 2 * w + ct;
            w2r[ct][ks] = *(const f16x8*)(w2g + (((ctg << 3) + ks) << 9) + (l << 3));
        }
#pragma unroll
    for (int ct = 0; ct < 2; ++ct) {
#pragma unroll
        for (int ks = 0; ks < 2; ++ks) pin_reg(w1r[ct][ks]);
#pragma unroll
        for (int ks = 0; ks < 8; ++ks) pin_reg(w2r[ct][ks]);
    }
    f32x4 b1v[2], b2v[2];
#pragma unroll
    for (int ct = 0; ct < 2; ++ct) {
        int c0 = wb + ct * 16 + fg * 4;
        b1v[ct] = *(const f32x4*)(pb1 + c0);
        b2v[ct] = *(const f32x4*)(pb2 + c0);
    }

    float psum[2][4] = {{0.f, 0.f, 0.f, 0.f}, {0.f, 0.f, 0.f, 0.f}};

    const int t0 = blockIdx.x;
    // ---- prologue: stage tile t0 into xs[0], prefetch t0+NBLK into regs
    {
        const float4* xg = (const float4*)(x + (size_t)t0 * 4096);
#pragma unroll
        for (int i = 0; i < 2; ++i) {
            int f4 = tid + i * 512;
            float4 v = xg[f4];
            int row = f4 >> 4, c4 = f4 & 15;
            uint2 o;
            o.x = pk(v.x, v.y);
            o.y = pk(v.z, v.w);
            int byte = (row * 128 + c4 * 8) ^ ((row & 7) << 4);
            *(uint2*)((char*)xs[0] + byte) = o;
        }
    }
    float4 pf0, pf1;
    {
        int tn = (t0 + NBLK < ntiles) ? t0 + NBLK : 0;
        const float4* xg = (const float4*)(x + (size_t)tn * 4096);
        pf0 = xg[tid];
        pf1 = xg[tid + 512];
    }
    __syncthreads();

    int buf = 0, hb = 0;
    for (int t = t0; t < ntiles; t += NBLK) {
        // ---- stage next x tile FIRST (consume pf regs -> xs[buf^1])
#pragma unroll
        for (int i = 0; i < 2; ++i) {
            float4 v = i ? pf1 : pf0;
            int f4 = tid + i * 512;
            int row = f4 >> 4, c4 = f4 & 15;
            uint2 o;
            o.x = pk(v.x, v.y);
            o.y = pk(v.z, v.w);
            int byte = (row * 128 + c4 * 8) ^ ((row & 7) << 4);
            *(uint2*)((char*)xs[buf ^ 1] + byte) = o;
        }
        // ---- ISSUE global loads for t+2*NBLK now: they have all of GEMM1 to land
        {
            int tn = (t + 2 * NBLK < ntiles) ? t + 2 * NBLK : 0;
            const float4* xg = (const float4*)(x + (size_t)tn * 4096);
            pf0 = xg[tid];
            pf1 = xg[tid + 512];
        }

        // ---- GEMM1: D1 = (x@pw1)^T from xs[buf] -> h1s[hb]
        {
            f32x4 acc[2][4] = {};
#pragma unroll
            for (int ks = 0; ks < 2; ++ks) {
                f16x8 bd[4];
#pragma unroll
                for (int rt = 0; rt < 4; ++rt) {
                    int row = (rt << 4) + fr;
                    int byte = ((row << 7) + (ks << 6) + (fg << 4)) ^ ((row & 7) << 4);
                    bd[rt] = *(const f16x8*)((char*)xs[buf] + byte);
                }
#pragma unroll
                for (int ct = 0; ct < 2; ++ct)
#pragma unroll
                    for (int rt = 0; rt < 4; ++rt)
                        acc[ct][rt] = __builtin_amdgcn_mfma_f32_16x16x32_f16(w1r[ct][ks], bd[rt], acc[ct][rt], 0, 0, 0);
            }
            // epilogue: bias+relu, packed cvt; lane holds h-cols c0..c0+3 of row rown
#pragma unroll
            for (int ct = 0; ct < 2; ++ct) {
                int c0 = wb + ct * 16 + fg * 4;
#pragma unroll
                for (int rt = 0; rt < 4; ++rt) {
                    int rown = (rt << 4) + fr;
                    uint2 o;
                    o.x = pk(fmaxf(acc[ct][rt][0] + b1v[ct][0], 0.f),
                             fmaxf(acc[ct][rt][1] + b1v[ct][1], 0.f));
                    o.y = pk(fmaxf(acc[ct][rt][2] + b1v[ct][2], 0.f),
                             fmaxf(acc[ct][rt][3] + b1v[ct][3], 0.f));
                    int byte = ((rown << 9) + (c0 << 1)) ^ ((rown & 15) << 4);
                    *(uint2*)((char*)h1s[hb] + byte) = o;
                }
            }
        }
        __syncthreads();   // h1s[hb] + xs[buf^1] visible; prefetch loads landed

        // ---- GEMM2: D2 = (h1@pw2)^T, pool into psum
        {
            f32x4 acc2[2][4] = {};
#pragma unroll
            for (int ks = 0; ks < 8; ++ks) {
                f16x8 bd[4];
#pragma unroll
                for (int rt = 0; rt < 4; ++rt) {
                    int row = (rt << 4) + fr;
                    int byte = ((row << 9) + (ks << 6) + (fg << 4)) ^ ((row & 15) << 4);
                    bd[rt] = *(const f16x8*)((char*)h1s[hb] + byte);
                }
#pragma unroll
                for (int ct = 0; ct < 2; ++ct)
#pragma unroll
                    for (int rt = 0; rt < 4; ++rt)
                        acc2[ct][rt] = __builtin_amdgcn_mfma_f32_16x16x32_f16(w2r[ct][ks], bd[rt], acc2[ct][rt], 0, 0, 0);
            }
#pragma unroll
            for (int ct = 0; ct < 2; ++ct)
#pragma unroll
                for (int r = 0; r < 4; ++r) {
                    float v = 0.f;
#pragma unroll
                    for (int rt = 0; rt < 4; ++rt)
                        v += fmaxf(acc2[ct][rt][r] + b2v[ct][r], 0.f);
                    psum[ct][r] += v;
                }
        }
        buf ^= 1;
        hb ^= 1;
    }

    // ---- pool contribution: reduce psum over the 16 fr-lanes, atomicAdd
#pragma unroll
    for (int ct = 0; ct < 2; ++ct)
#pragma unroll
        for (int r = 0; r < 4; ++r) {
            float v = psum[ct][r];
            v += __shfl_xor(v, 1, 64);
            v += __shfl_xor(v, 2, 64);
            v += __shfl_xor(v, 4, 64);
            v += __shfl_xor(v, 8, 64);
            if (fr == 0) atomicAdd(&gsum[wb + ct * 16 + fg * 4 + r], v);
        }

    // ---- last-block tail: f16x4 rho + head with 512 threads -----------------
    __threadfence();
    if (tid == 0) {
        int old = atomicAdd((int*)(gsum + 256), 1);
        lastflag = (old == NBLK - 1);
    }
    __syncthreads();
    if (!lastflag) return;
    __threadfence();   // acquire all blocks' gsum contributions

    float* sb  = (float*)h1s;            // carve dead h1s (64KB)
    float* fp  = sb;                     // 128
    float* r1v = sb + 128;               // 256
    float* r2v = sb + 384;               // 256
    float* tcv = sb + 640;               // 144
    float* t1v = sb + 784;               // 256
    float* t2v = sb + 1040;              // 256
    float* part = sb + 1296;             // 2048 (16B-aligned: 1296*4=5184)
    const int t = tid;

    // fp = nf*pb3 + gsum @ pw3       (256->128: 32cg x 16q, KR=16)
    LAYER_V4(128, OPW3, gsum[i], nf * pb3[t], fp, 0, 16, 16)
    // r1 = relu(fp @ rw1 + rb1)      (128->256: 64cg x 8q, KR=16)
    LAYER_V4(256, ORW1, fp[i], rb1[t], r1v, 1, 8, 16)
    // r2 = relu(r1 @ rw2 + rb2)      (256->256: KR=32)
    LAYER_V4(256, ORW2, r1v[i], rb2[t], r2v, 1, 8, 32)
    // tc[0:128] = r2 @ rw3 + rb3     (256->128: KR=16)
    LAYER_V4(128, ORW3, r2v[i], rb3[t], tcv, 0, 16, 16)
    if (t >= 128 && t < 144) tcv[t] = xst[t - 128];
    __syncthreads();
    // t1 = relu(tc @ hw1 + hb1)      (144->256: KR=18)
    LAYER_V4(256, OHW1, tcv[i], hb1[t], t1v, 1, 8, 18)
    // t2 = relu(t1 @ hw2 + hb2)      (256->256: KR=32)
    LAYER_V4(256, OHW2, t1v[i], hb2[t], t2v, 1, 8, 32)
    // out = t2 @ hw3 + hb3           (256->5: scalar, 2-way x 128)
    {
        int j = t & 255, q = t >> 8, b = 128 * q;
        if (j < 5) {
            float s0 = 0.f, s1 = 0.f;
#pragma unroll
            for (int i = 0; i < 128; i += 2) {
                s0 += t2v[b + i]     * (float)tw[OHW3 + (b + i) * 5 + j];
                s1 += t2v[b + i + 1] * (float)tw[OHW3 + (b + i + 1) * 5 + j];
            }
            part[q * 8 + j] = s0 + s1;
        }
    }
    __syncthreads();
    if (t < 5) outp[t] = hb3[t] + part[t] + part[8 + t];
}

extern "C" void kernel_launch(void* const* d_in, const int* in_sizes, int n_in,
                              void* d_out, int out_size, void* d_ws, size_t ws_size,
                              hipStream_t stream) {
    (void)n_in; (void)out_size; (void)ws_size;
    const float* x   = (const float*)d_in[0];
    const float* xst = (const float*)d_in[1];
    const float* pw1 = (const float*)d_in[2];
    const float* pb1 = (const float*)d_in[3];
    const float* pw2 = (const float*)d_in[4];
    const float* pb2 = (const float*)d_in[5];
    const float* pw3 = (const float*)d_in[6];
    const float* pb3 = (const float*)d_in[7];
    const float* rw1 = (const float*)d_in[8];
    const float* rb1 = (const float*)d_in[9];
    const float* rw2 = (const float*)d_in[10];
    const float* rb2 = (const float*)d_in[11];
    const float* rw3 = (const float*)d_in[12];
    const float* rb3 = (const float*)d_in[13];
    const float* w1  = (const float*)d_in[14];
    const float* b1  = (const float*)d_in[15];
    const float* w2  = (const float*)d_in[16];
    const float* b2  = (const float*)d_in[17];
    const float* w3  = (const float*)d_in[18];
    const float* b3  = (const float*)d_in[19];
    float* out = (float*)d_out;

    int n = in_sizes[0] / 64;      // 400000
    int ntiles = n >> 6;           // 6250

    char* ws = (char*)d_ws;
    float* gsum = (float*)ws;                        // 256 f32 + counter (2KB pad)
    _Float16* w1f = (_Float16*)(ws + 2048);          // 16384 f16 (32KB)
    _Float16* w2f = (_Float16*)(ws + 2048 + 32768);  // 65536 f16 (128KB)
    _Float16* tw  = (_Float16*)(ws + 2048 + 32768 + 131072);  // 267520 f16 (~523KB)

    prep_kernel<<<160, 512, 0, stream>>>(pw1, pw2, w1f, w2f, gsum, tw,
                                         pw3, rw1, rw2, rw3, w1, w2, w3);
    phi_kernel<<<NBLK, 512, 0, stream>>>(x, pb1, pb2, w1f, w2f, gsum, ntiles,
                                         xst, tw, pb3, rb1, rb2, rb3,
                                         b1, b2, b3, out, (float)n);
}

// Round 20
// 101.854 us; speedup vs baseline: 1.2509x; 1.2509x over previous
//
#include <hip/hip_runtime.h>

// DeepSets fused kernel for MI355X (gfx950) — round 20 (revert to r18 champion).
// r19 post-mortem: fused last-block tail costs ~43-48us REGARDLESS of tail body
// (r16: 48 w/ scalar fp32; r19: 43 w/ f16x4) -> the cost is 256 serialized
// device-scope RMWs on one cacheline ping-ponging across 8 non-coherent XCD
// L2s (~150-200ns each ~= 40-50us). Sharded counter would fix it but fusion's
// net ROI is -1..+3us -> abandoned. This is r18 verbatim: 102.3us total =
// phi 85.8 (structural floor, 6 attacks hit the 2-waves/SIMD register wall)
// + prep ~1 + 2 launch gaps ~10 + f16x4 tail ~5.

typedef unsigned short u16;
typedef _Float16 f16x8 __attribute__((ext_vector_type(8)));
typedef _Float16 f16x4v __attribute__((ext_vector_type(4)));
typedef float f32x4 __attribute__((ext_vector_type(4)));
typedef int i32x4 __attribute__((ext_vector_type(4)));

#define NBLK 256

// packed fp16 tail-weight offsets (elements); all divisible by 4
#define OPW3 0        // 256x128
#define ORW1 32768    // 128x256
#define ORW2 65536    // 256x256
#define ORW3 131072   // 256x128
#define OHW1 163840   // 144x256
#define OHW2 200704   // 256x256
#define OHW3 266240   // 256x5
#define NTW  267520

// ---------------- prep: phi-weight fragments + packed fp16 tail weights ------
// Fragment layout (validated r1-r12): lane l, elem j holds W[k=32*ks+8*(l>>4)+j][16*ctg+(l&15)]
// at frag[((ctg*KS+ks)*64 + l)*8 + j]. Used as MFMA *A* operand: D = W^T X^T = (XW)^T.
__global__ void prep_kernel(const float* __restrict__ pw1, const float* __restrict__ pw2,
                            _Float16* __restrict__ w1f, _Float16* __restrict__ w2f,
                            float* __restrict__ gsum, _Float16* __restrict__ tw,
                            const float* __restrict__ pw3, const float* __restrict__ rw1,
                            const float* __restrict__ rw2, const float* __restrict__ rw3,
                            const float* __restrict__ hw1, const float* __restrict__ hw2,
                            const float* __restrict__ hw3) {
    int idx = blockIdx.x * blockDim.x + threadIdx.x;   // 160*512 = 81920
    if (idx < 256) gsum[idx] = 0.f;
    if (idx < 16384) {  // pw1: 64x256, KS=2
        int j = idx & 7, l = (idx >> 3) & 63, ks = (idx >> 9) & 1, ct = idx >> 10;
        int k = 32 * ks + 8 * (l >> 4) + j;
        int col = 16 * ct + (l & 15);
        w1f[idx] = (_Float16)pw1[k * 256 + col];
    } else {            // pw2: 256x256, KS=8
        int o = idx - 16384;
        int j = o & 7, l = (o >> 3) & 63, ks = (o >> 9) & 7, ct = o >> 12;
        int k = 32 * ks + 8 * (l >> 4) + j;
        int col = 16 * ct + (l & 15);
        w2f[o] = (_Float16)pw2[k * 256 + col];
    }
    // pack rho/head weights to fp16, float4 -> f16x4 (write also L3-warms)
    if (idx < NTW / 4) {
        int r = idx * 4;
        const float* src;
        if (r < ORW1)      src = pw3 + r;
        else if (r < ORW2) src = rw1 + (r - ORW1);
        else if (r < ORW3) src = rw2 + (r - ORW2);
        else if (r < OHW1) src = rw3 + (r - ORW3);
        else if (r < OHW2) src = hw1 + (r - OHW1);
        else if (r < OHW3) src = hw2 + (r - OHW2);
        else               src = hw3 + (r - OHW3);
        float4 v = *(const float4*)src;
        uint2 o;
        o.x = __builtin_bit_cast(unsigned, __builtin_amdgcn_cvt_pkrtz(v.x, v.y));
        o.y = __builtin_bit_cast(unsigned, __builtin_amdgcn_cvt_pkrtz(v.z, v.w));
        *(uint2*)(tw + r) = o;
    }
}

__device__ __forceinline__ void pin_reg(f16x8& v) {
    i32x4 t = __builtin_bit_cast(i32x4, v);
    asm volatile("" : "+v"(t));
    v = __builtin_bit_cast(f16x8, t);
}
__device__ __forceinline__ unsigned pk(float a, float b) {
    return __builtin_bit_cast(unsigned, __builtin_amdgcn_cvt_pkrtz(a, b));
}

// ---------------- fused phi + pool (persistent, r12-exact) -------------------
// 8 waves; wave w owns cols [32w, 32w+32); dbuf xs + dbuf h1s, ONE barrier/iter.
__global__ __attribute__((amdgpu_flat_work_group_size(512, 512), amdgpu_waves_per_eu(2, 2)))
void phi_kernel(
    const float* __restrict__ x,
    const float* __restrict__ pb1, const float* __restrict__ pb2,
    const _Float16* __restrict__ w1g, const _Float16* __restrict__ w2g,
    float* __restrict__ gsum, int ntiles) {
    __shared__ __align__(16) u16 xs[2][64 * 64];    // x tile fp16, swz ^((row&7)<<4)
    __shared__ __align__(16) u16 h1s[2][64 * 256];  // h1 tile fp16, swz ^((row&15)<<4)

    const int tid = threadIdx.x;
    const int l = tid & 63;
    const int w = tid >> 6;
    const int fr = l & 15;
    const int fg = l >> 4;
    const int wb = w * 32;

    // ---- preload weight fragments into registers (loop-invariant, pinned)
    f16x8 w1r[2][2];   // [ct][ks]
#pragma unroll
    for (int ct = 0; ct < 2; ++ct)
#pragma unroll
        for (int ks = 0; ks < 2; ++ks) {
            int ctg = 2 * w + ct;
            w1r[ct][ks] = *(const f16x8*)(w1g + (((ctg << 1) + ks) << 9) + (l << 3));
        }
    f16x8 w2r[2][8];   // [ct][ks]
#pragma unroll
    for (int ct = 0; ct < 2; ++ct)
#pragma unroll
        for (int ks = 0; ks < 8; ++ks) {
            int ctg = 2 * w + ct;
            w2r[ct][ks] = *(const f16x8*)(w2g + (((ctg << 3) + ks) << 9) + (l << 3));
        }
#pragma unroll
    for (int ct = 0; ct < 2; ++ct) {
#pragma unroll
        for (int ks = 0; ks < 2; ++ks) pin_reg(w1r[ct][ks]);
#pragma unroll
        for (int ks = 0; ks < 8; ++ks) pin_reg(w2r[ct][ks]);
    }
    f32x4 b1v[2], b2v[2];
#pragma unroll
    for (int ct = 0; ct < 2; ++ct) {
        int c0 = wb + ct * 16 + fg * 4;
        b1v[ct] = *(const f32x4*)(pb1 + c0);
        b2v[ct] = *(const f32x4*)(pb2 + c0);
    }

    float psum[2][4] = {{0.f, 0.f, 0.f, 0.f}, {0.f, 0.f, 0.f, 0.f}};

    const int t0 = blockIdx.x;
    // ---- prologue: stage tile t0 into xs[0], prefetch t0+NBLK into regs
    {
        const float4* xg = (const float4*)(x + (size_t)t0 * 4096);
#pragma unroll
        for (int i = 0; i < 2; ++i) {
            int f4 = tid + i * 512;
            float4 v = xg[f4];
            int row = f4 >> 4, c4 = f4 & 15;
            uint2 o;
            o.x = pk(v.x, v.y);
            o.y = pk(v.z, v.w);
            int byte = (row * 128 + c4 * 8) ^ ((row & 7) << 4);
            *(uint2*)((char*)xs[0] + byte) = o;
        }
    }
    float4 pf0, pf1;
    {
        int tn = (t0 + NBLK < ntiles) ? t0 + NBLK : 0;
        const float4* xg = (const float4*)(x + (size_t)tn * 4096);
        pf0 = xg[tid];
        pf1 = xg[tid + 512];
    }
    __syncthreads();

    int buf = 0, hb = 0;
    for (int t = t0; t < ntiles; t += NBLK) {
        // ---- stage next x tile FIRST (consume pf regs -> xs[buf^1])
#pragma unroll
        for (int i = 0; i < 2; ++i) {
            float4 v = i ? pf1 : pf0;
            int f4 = tid + i * 512;
            int row = f4 >> 4, c4 = f4 & 15;
            uint2 o;
            o.x = pk(v.x, v.y);
            o.y = pk(v.z, v.w);
            int byte = (row * 128 + c4 * 8) ^ ((row & 7) << 4);
            *(uint2*)((char*)xs[buf ^ 1] + byte) = o;
        }
        // ---- ISSUE global loads for t+2*NBLK now: they have all of GEMM1 to land
        {
            int tn = (t + 2 * NBLK < ntiles) ? t + 2 * NBLK : 0;
            const float4* xg = (const float4*)(x + (size_t)tn * 4096);
            pf0 = xg[tid];
            pf1 = xg[tid + 512];
        }

        // ---- GEMM1: D1 = (x@pw1)^T from xs[buf] -> h1s[hb]
        {
            f32x4 acc[2][4] = {};
#pragma unroll
            for (int ks = 0; ks < 2; ++ks) {
                f16x8 bd[4];
#pragma unroll
                for (int rt = 0; rt < 4; ++rt) {
                    int row = (rt << 4) + fr;
                    int byte = ((row << 7) + (ks << 6) + (fg << 4)) ^ ((row & 7) << 4);
                    bd[rt] = *(const f16x8*)((char*)xs[buf] + byte);
                }
#pragma unroll
                for (int ct = 0; ct < 2; ++ct)
#pragma unroll
                    for (int rt = 0; rt < 4; ++rt)
                        acc[ct][rt] = __builtin_amdgcn_mfma_f32_16x16x32_f16(w1r[ct][ks], bd[rt], acc[ct][rt], 0, 0, 0);
            }
            // epilogue: bias+relu, packed cvt; lane holds h-cols c0..c0+3 of row rown
#pragma unroll
            for (int ct = 0; ct < 2; ++ct) {
                int c0 = wb + ct * 16 + fg * 4;
#pragma unroll
                for (int rt = 0; rt < 4; ++rt) {
                    int rown = (rt << 4) + fr;
                    uint2 o;
                    o.x = pk(fmaxf(acc[ct][rt][0] + b1v[ct][0], 0.f),
                             fmaxf(acc[ct][rt][1] + b1v[ct][1], 0.f));
                    o.y = pk(fmaxf(acc[ct][rt][2] + b1v[ct][2], 0.f),
                             fmaxf(acc[ct][rt][3] + b1v[ct][3], 0.f));
                    int byte = ((rown << 9) + (c0 << 1)) ^ ((rown & 15) << 4);
                    *(uint2*)((char*)h1s[hb] + byte) = o;
                }
            }
        }
        __syncthreads();   // h1s[hb] + xs[buf^1] visible; prefetch loads landed

        // ---- GEMM2: D2 = (h1@pw2)^T, pool into psum
        {
            f32x4 acc2[2][4] = {};
#pragma unroll
            for (int ks = 0; ks < 8; ++ks) {
                f16x8 bd[4];
#pragma unroll
                for (int rt = 0; rt < 4; ++rt) {
                    int row = (rt << 4) + fr;
                    int byte = ((row << 9) + (ks << 6) + (fg << 4)) ^ ((row & 15) << 4);
                    bd[rt] = *(const f16x8*)((char*)h1s[hb] + byte);
                }
#pragma unroll
                for (int ct = 0; ct < 2; ++ct)
#pragma unroll
                    for (int rt = 0; rt < 4; ++rt)
                        acc2[ct][rt] = __builtin_amdgcn_mfma_f32_16x16x32_f16(w2r[ct][ks], bd[rt], acc2[ct][rt], 0, 0, 0);
            }
#pragma unroll
            for (int ct = 0; ct < 2; ++ct)
#pragma unroll
                for (int r = 0; r < 4; ++r) {
                    float v = 0.f;
#pragma unroll
                    for (int rt = 0; rt < 4; ++rt)
                        v += fmaxf(acc2[ct][rt][r] + b2v[ct][r], 0.f);
                    psum[ct][r] += v;
                }
        }
        buf ^= 1;
        hb ^= 1;
    }

    // ---- final: reduce psum over the 16 fr-lanes, one atomicAdd per col
#pragma unroll
    for (int ct = 0; ct < 2; ++ct)
#pragma unroll
        for (int r = 0; r < 4; ++r) {
            float v = psum[ct][r];
            v += __shfl_xor(v, 1, 64);
            v += __shfl_xor(v, 2, 64);
            v += __shfl_xor(v, 4, 64);
            v += __shfl_xor(v, 8, 64);
            if (fr == 0) atomicAdd(&gsum[wb + ct * 16 + fg * 4 + r], v);
        }
}

// ---------------- tail: f16x4-vectorized split-K rho + head (1024 thr) -------
// Per layer: thread owns 4 output cols x KR input rows; all weight loads f16x4.
#define LAYER_V4(IN, OUT, OFF, INEXPR, BIASEXPR, OUTARR, DORELU, KQ, KR)       \
    {                                                                          \
        int cg = t & ((OUT) / 4 - 1), q = t / ((OUT) / 4);                     \
        float4 s = make_float4(0.f, 0.f, 0.f, 0.f);                            \
        int i0 = q * (KR);                                                     \
        for (int i = i0; i < i0 + (KR); ++i) {                                 \
            f16x4v wv = *(const f16x4v*)(tw + (OFF) + i * (OUT) + 4 * cg);     \
            float xv = INEXPR;                                                 \
            s.x += xv * (float)wv[0]; s.y += xv * (float)wv[1];                \
            s.z += xv * (float)wv[2]; s.w += xv * (float)wv[3];                \
        }                                                                      \
        *(float4*)&part[q * (OUT) + 4 * cg] = s;                               \
    }                                                                          \
    __syncthreads();                                                           \
    if (t < (OUT)) {                                                           \
        float s = BIASEXPR;                                                    \
        for (int q = 0; q < (KQ); ++q) s += part[q * (OUT) + t];               \
        OUTARR[t] = (DORELU) ? fmaxf(s, 0.f) : s;                              \
    }                                                                          \
    __syncthreads();

__global__ __launch_bounds__(1024) void tail_kernel(
    const float* __restrict__ gsum, const float* __restrict__ xst,
    const _Float16* __restrict__ tw,
    const float* __restrict__ pb3, const float* __restrict__ rb1,
    const float* __restrict__ rb2, const float* __restrict__ rb3,
    const float* __restrict__ hb1, const float* __restrict__ hb2,
    const float* __restrict__ hb3,
    float* __restrict__ out, float nf) {
    __shared__ float fp[128], r1[256], r2[256], tc[144], t1[256], t2[256];
    __shared__ __align__(16) float part[4096];   // 32x128 or 16x256
    const int t = threadIdx.x;

    // fp = nf*pb3 + gsum @ pw3          (256->128: 32 cg x 32 q, KR=8)
    LAYER_V4(256, 128, OPW3, gsum[i], nf * pb3[t], fp, 0, 32, 8)
    // r1 = relu(fp @ rw1 + rb1)         (128->256: 64 cg x 16 q, KR=8)
    LAYER_V4(128, 256, ORW1, fp[i], rb1[t], r1, 1, 16, 8)
    // r2 = relu(r1 @ rw2 + rb2)         (256->256: KR=16)
    LAYER_V4(256, 256, ORW2, r1[i], rb2[t], r2, 1, 16, 16)
    // tc[0:128] = r2 @ rw3 + rb3        (256->128: KR=8)
    LAYER_V4(256, 128, ORW3, r2[i], rb3[t], tc, 0, 32, 8)
    if (t >= 128 && t < 144) tc[t] = xst[t - 128];
    __syncthreads();
    // t1 = relu(tc @ hw1 + hb1)         (144->256: KR=9)
    LAYER_V4(144, 256, OHW1, tc[i], hb1[t], t1, 1, 16, 9)
    // t2 = relu(t1 @ hw2 + hb2)         (256->256: KR=16)
    LAYER_V4(256, 256, OHW2, t1[i], hb2[t], t2, 1, 16, 16)
    // out = t2 @ hw3 + hb3              (256->5: scalar, 4-way x 64)
    {
        int j = t & 255, q = t >> 8, b = 64 * q;
        if (j < 5) {
            float s0 = 0.f, s1 = 0.f;
#pragma unroll
            for (int i = 0; i < 64; i += 2) {
                s0 += t2[b + i]     * (float)tw[OHW3 + (b + i) * 5 + j];
                s1 += t2[b + i + 1] * (float)tw[OHW3 + (b + i + 1) * 5 + j];
            }
            part[q * 8 + j] = s0 + s1;
        }
    }
    __syncthreads();
    if (t < 5) {
        float s = hb3[t];
        for (int q = 0; q < 4; ++q) s += part[q * 8 + t];
        out[t] = s;
    }
}

extern "C" void kernel_launch(void* const* d_in, const int* in_sizes, int n_in,
                              void* d_out, int out_size, void* d_ws, size_t ws_size,
                              hipStream_t stream) {
    (void)n_in; (void)out_size; (void)ws_size;
    const float* x   = (const float*)d_in[0];
    const float* xst = (const float*)d_in[1];
    const float* pw1 = (const float*)d_in[2];
    const float* pb1 = (const float*)d_in[3];
    const float* pw2 = (const float*)d_in[4];
    const float* pb2 = (const float*)d_in[5];
    const float* pw3 = (const float*)d_in[6];
    const float* pb3 = (const float*)d_in[7];
    const float* rw1 = (const float*)d_in[8];
    const float* rb1 = (const float*)d_in[9];
    const float* rw2 = (const float*)d_in[10];
    const float* rb2 = (const float*)d_in[11];
    const float* rw3 = (const float*)d_in[12];
    const float* rb3 = (const float*)d_in[13];
    const float* w1  = (const float*)d_in[14];
    const float* b1  = (const float*)d_in[15];
    const float* w2  = (const float*)d_in[16];
    const float* b2  = (const float*)d_in[17];
    const float* w3  = (const float*)d_in[18];
    const float* b3  = (const float*)d_in[19];
    float* out = (float*)d_out;

    int n = in_sizes[0] / 64;      // 400000
    int ntiles = n >> 6;           // 6250

    char* ws = (char*)d_ws;
    float* gsum = (float*)ws;                        // 256 f32 (1KB, pad to 2KB)
    _Float16* w1f = (_Float16*)(ws + 2048);          // 16384 f16 (32KB)
    _Float16* w2f = (_Float16*)(ws + 2048 + 32768);  // 65536 f16 (128KB)
    _Float16* tw  = (_Float16*)(ws + 2048 + 32768 + 131072);  // 267520 f16 (~523KB)

    prep_kernel<<<160, 512, 0, stream>>>(pw1, pw2, w1f, w2f, gsum, tw,
                                         pw3, rw1, rw2, rw3, w1, w2, w3);
    phi_kernel<<<NBLK, 512, 0, stream>>>(x, pb1, pb2, w1f, w2f, gsum, ntiles);
    tail_kernel<<<1, 1024, 0, stream>>>(gsum, xst, tw, pb3, rb1, rb2, rb3,
                                        b1, b2, b3, out, (float)n);
}